// Round 1
// baseline (15477.939 us; speedup 1.0000x reference)
//
#include <hip/hip_runtime.h>
#include <math.h>

// Problem constants
#define Bz   32
#define Nn   128
#define Hh   256
#define Dd   256
#define Ff   512
#define Gg   768      // 3*H
#define NBLK 8        // blocks per batch element
#define NT   256      // threads per block

// Workspace layout (float elements)
#define WS_H0     0                               // [B][H]
#define WS_GH0    (WS_H0 + Bz*Hh)                 // [B][G]   h0@Wh+bh
#define WS_ZW1    (WS_GH0 + Bz*Gg)                // [B][F]   z@W1c
#define WS_HPROV  (WS_ZW1 + Bz*Ff)                // [B][H]
#define WS_GX2    (WS_HPROV + Bz*Hh)              // [B][G]   pooled2@Wx+bx
#define WS_HW1    (WS_GX2 + Bz*Gg)                // [B][F]   h_prov@W1a
#define WS_GHT    (WS_HW1 + Bz*Ff)                // [B][G]   h_prov@Wh+bh
#define WS_SLOTS  (WS_GHT + Bz*Gg)                // [2][B][NBLK][H] pooled partial sums
#define WS_WXP    (WS_SLOTS + 2*Bz*NBLK*Hh)       // [128][768] bf16x2 packed Wx
#define WS_WHP    (WS_WXP + (Hh/2)*Gg)            // [128][768] packed Wh
#define WS_W1BP   (WS_WHP + (Hh/2)*Gg)            // [128][512] packed W1 rows 256..511
#define WS_W1AP   (WS_W1BP + (Hh/2)*Ff)           // [128][512] packed W1 rows 0..255
#define WS_A      (WS_W1AP + (Hh/2)*Ff)           // [B][N][N] uint8 ancestor bitset
#define WS_BAR    (WS_A + (Bz*Nn*Nn)/4)           // [B][16] uint barrier counters
#define WS_TOTAL  (WS_BAR + Bz*16)                // ~2.85 MB

__device__ __forceinline__ float bf2f_lo(unsigned w) { return __uint_as_float(w << 16); }
__device__ __forceinline__ float bf2f_hi(unsigned w) { return __uint_as_float(w & 0xffff0000u); }
__device__ __forceinline__ unsigned short f2bf(float x) {
  unsigned u = __float_as_uint(x);
  u = u + 0x7fffu + ((u >> 16) & 1u);   // RNE
  return (unsigned short)(u >> 16);
}
__device__ __forceinline__ unsigned pack2(float e, float o) {
  return (unsigned)f2bf(e) | ((unsigned)f2bf(o) << 16);
}
__device__ __forceinline__ float sigm(float x) { return 1.0f / (1.0f + __expf(-x)); }

// Per-batch barrier: monotonic counter, 8 arrivals per barrier instance.
__device__ __forceinline__ void bbarrier(unsigned* cnt, unsigned& seq)
{
  __syncthreads();
  seq += NBLK;
  if (threadIdx.x == 0) {
    __threadfence();
    __hip_atomic_fetch_add(cnt, 1u, __ATOMIC_RELEASE, __HIP_MEMORY_SCOPE_AGENT);
    while (__hip_atomic_load(cnt, __ATOMIC_ACQUIRE, __HIP_MEMORY_SCOPE_AGENT) < seq) {
      __builtin_amdgcn_s_sleep(2);
    }
    __threadfence();
  }
  __syncthreads();
}

// ---------- prep 1: output L, zero init, pack weights to bf16 pairs ----------
__global__ void __launch_bounds__(NT) prep_init(
    const int* __restrict__ tg, const float* __restrict__ Wx,
    const float* __restrict__ Wh, const float* __restrict__ W1,
    float* __restrict__ ws, float* __restrict__ out)
{
  const int stride = gridDim.x * blockDim.x;
  const int t0 = blockIdx.x * blockDim.x + threadIdx.x;

  for (int i = t0; i < Bz*Nn*Nn; i += stride) {         // L = tril(targets, -1)
    int col = i & (Nn-1), row = (i >> 7) & (Nn-1);
    out[i] = (col < row) ? (float)tg[i] : 0.0f;
  }
  for (int i = t0; i < Bz; i += stride) out[Bz*Nn*Nn + i] = 0.0f;   // ll = 0

  unsigned* Aw = (unsigned*)(ws + WS_A);
  for (int i = t0; i < (Bz*Nn*Nn)/4; i += stride) Aw[i] = 0u;
  for (int i = t0; i < 2*Bz*NBLK*Hh; i += stride) ws[WS_SLOTS + i] = 0.0f;
  unsigned* bar = (unsigned*)(ws + WS_BAR);
  for (int i = t0; i < Bz*16; i += stride) bar[i] = 0u;

  unsigned* Wxp  = (unsigned*)(ws + WS_WXP);
  unsigned* Whp  = (unsigned*)(ws + WS_WHP);
  for (int i = t0; i < (Hh/2)*Gg; i += stride) {
    int k2 = i / Gg, g = i - k2*Gg;
    Wxp[i] = pack2(Wx[(2*k2)*Gg + g], Wx[(2*k2+1)*Gg + g]);
    Whp[i] = pack2(Wh[(2*k2)*Gg + g], Wh[(2*k2+1)*Gg + g]);
  }
  unsigned* W1bp = (unsigned*)(ws + WS_W1BP);
  unsigned* W1ap = (unsigned*)(ws + WS_W1AP);
  for (int i = t0; i < (Hh/2)*Ff; i += stride) {
    int k2 = i / Ff, f = i - k2*Ff;
    W1ap[i] = pack2(W1[(2*k2)*Ff + f],      W1[(2*k2+1)*Ff + f]);
    W1bp[i] = pack2(W1[(Hh+2*k2)*Ff + f],   W1[(Hh+2*k2+1)*Ff + f]);
  }
}

// ---------- prep 2: per-batch h0, gh0 = h0@Wh+bh, zW1 = z@W1c (fp32) ----------
__global__ void __launch_bounds__(NT) prep_batch(
    const float* __restrict__ z, const float* __restrict__ Wi,
    const float* __restrict__ bi, const float* __restrict__ Wh,
    const float* __restrict__ bh, const float* __restrict__ W1,
    float* __restrict__ ws)
{
  const int b = blockIdx.x, tid = threadIdx.x;
  __shared__ float zs[Dd], h0s[Hh];
  zs[tid] = z[b*Dd + tid];
  __syncthreads();
  float acc = bi[tid];
  for (int d = 0; d < Dd; ++d) acc = fmaf(zs[d], Wi[d*Hh + tid], acc);
  const float h0 = tanhf(acc);
  h0s[tid] = h0;
  ws[WS_H0 + b*Hh + tid] = h0;
  ws[WS_SLOTS + ((1*Bz + b)*NBLK + 0)*Hh + tid] = h0;   // pooled sum for t=1 (parity 1, slot r=0)
  __syncthreads();
  for (int g = tid; g < Gg; g += NT) {
    float a = bh[g];
    for (int h = 0; h < Hh; ++h) a = fmaf(h0s[h], Wh[h*Gg + g], a);
    ws[WS_GH0 + b*Gg + g] = a;
  }
  for (int f = tid; f < Ff; f += NT) {
    float a = 0.0f;
    for (int d = 0; d < Dd; ++d) a = fmaf(zs[d], W1[(2*Hh + d)*Ff + f], a);
    ws[WS_ZW1 + b*Ff + f] = a;
  }
}

// ---------- main persistent decoder: 32 b x 8 blocks, 3 per-b barriers/step ----------
__global__ void __launch_bounds__(NT) decoder_main(
    const int* __restrict__ tg,
    const float* __restrict__ bx, const float* __restrict__ bh,
    const float* __restrict__ b1, const float* __restrict__ W2,
    const float* __restrict__ b2,
    float* __restrict__ ws, float* __restrict__ out)
{
  const int blk = blockIdx.x;
  const int b = blk >> 3;
  const int r = blk & 7;            // which 1/8 of rows (j % 8 == r) this block owns
  const int tid = threadIdx.x;
  const int lane = tid & 63;
  const int wv = tid >> 6;

  const unsigned* __restrict__ Wxp  = (const unsigned*)(ws + WS_WXP);
  const unsigned* __restrict__ Whp  = (const unsigned*)(ws + WS_WHP);
  const unsigned* __restrict__ W1bp = (const unsigned*)(ws + WS_W1BP);
  unsigned char* Ab = (unsigned char*)(ws + WS_A) + b*Nn*Nn;
  unsigned* bar = (unsigned*)(ws + WS_BAR) + b*16;

  __shared__ __align__(16) float S[16][Hh];   // owned state rows, fp32, block-private
  __shared__ float psum[Hh], hpf[Hh], p2s[Hh], psnext[Hh];
  __shared__ float gx2s[Gg];
  __shared__ float base[Ff], w2s[Ff];
  __shared__ float rowt[Nn];
  __shared__ float gxs[96];
  __shared__ float wred[4][2];

  #pragma unroll
  for (int i = 0; i < 16; ++i) S[i][tid] = 0.0f;   // states start at zero
  if (r == 0) S[0][tid] = ws[WS_H0 + b*Hh + tid];  // states[0] = h0
  w2s[tid] = W2[tid]; w2s[tid+NT] = W2[tid+NT];
  const float bhr = bh[tid], bhu = bh[tid+256], bhn = bh[tid+512];
  const float b2v = b2[0];
  float llacc = 0.0f;
  unsigned bseq = 0;
  __syncthreads();

  for (int t = 1; t < Nn; ++t) {
    const int p = t & 1;
    const float invt  = 1.0f / (float)t;
    const float invt1 = 1.0f / (float)(t+1);

    // ---------- Work A: pooled sum, h_prov slice ----------
    {
      float s = 0.0f;
      #pragma unroll
      for (int rr = 0; rr < NBLK; ++rr)
        s += ws[WS_SLOTS + ((p*Bz + b)*NBLK + rr)*Hh + tid];
      psum[tid] = s;
    }
    __syncthreads();
    if (tid < 96) {   // gx = pooled@Wx+bx for gates of h-slice [r*32, r*32+32)
      const int c = (tid >> 5)*256 + r*32 + (tid & 31);
      float acc = 0.0f;
      for (int k2 = 0; k2 < Hh/2; ++k2) {
        const unsigned w = Wxp[k2*Gg + c];
        const float2 sv = *(const float2*)&psum[2*k2];
        acc = fmaf(bf2f_lo(w), sv.x, fmaf(bf2f_hi(w), sv.y, acc));
      }
      gxs[tid] = acc * invt + bx[c];
    }
    __syncthreads();
    if (tid < 32) {   // h_prov slice -> ws (GRU with h = h0, gh = gh0)
      const int h = r*32 + tid;
      const float gr  = gxs[tid]    + ws[WS_GH0 + b*Gg + h];
      const float gu  = gxs[tid+32] + ws[WS_GH0 + b*Gg + 256 + h];
      const float gnx = gxs[tid+64];
      const float gnh = ws[WS_GH0 + b*Gg + 512 + h];
      const float rv = sigm(gr), uv = sigm(gu);
      const float nv = tanhf(gnx + rv*gnh);
      ws[WS_HPROV + b*Hh + h] = (1.0f-uv)*nv + uv*ws[WS_H0 + b*Hh + h];
    }
    bbarrier(bar, bseq);   // B1: h_prov complete

    // ---------- Work B: gx2, ght, hW1 slices ----------
    hpf[tid] = ws[WS_HPROV + b*Hh + tid];
    p2s[tid] = (psum[tid] + hpf[tid]) * invt1;   // pooled2
    __syncthreads();
    if (tid < 96) {
      const int c = r*96 + tid;
      float acc = 0.0f;
      for (int k2 = 0; k2 < Hh/2; ++k2) {
        const unsigned w = Wxp[k2*Gg + c];
        const float2 sv = *(const float2*)&p2s[2*k2];
        acc = fmaf(bf2f_lo(w), sv.x, fmaf(bf2f_hi(w), sv.y, acc));
      }
      ws[WS_GX2 + b*Gg + c] = acc + bx[c];
    } else if (tid < 192) {
      const int c = r*96 + (tid - 96);
      float acc = 0.0f;
      for (int k2 = 0; k2 < Hh/2; ++k2) {
        const unsigned w = Whp[k2*Gg + c];
        const float2 sv = *(const float2*)&hpf[2*k2];
        acc = fmaf(bf2f_lo(w), sv.x, fmaf(bf2f_hi(w), sv.y, acc));
      }
      ws[WS_GHT + b*Gg + c] = acc + bh[c];
    } else {
      const int f = r*64 + (tid - 192);
      const unsigned* W1ap = (const unsigned*)(ws + WS_W1AP);
      float acc = 0.0f;
      for (int k2 = 0; k2 < Hh/2; ++k2) {
        const unsigned w = W1ap[k2*Ff + f];
        const float2 sv = *(const float2*)&hpf[2*k2];
        acc = fmaf(bf2f_lo(w), sv.x, fmaf(bf2f_hi(w), sv.y, acc));
      }
      ws[WS_HW1 + b*Ff + f] = acc;
    }
    bbarrier(bar, bseq);   // B2: gx2/ght/hW1 complete

    // ---------- Work C: logits+ll, state updates, A row, pooled slot ----------
    for (int g = tid; g < Gg; g += NT) gx2s[g] = ws[WS_GX2 + b*Gg + g];
    base[tid]    = ws[WS_HW1 + b*Ff + tid]    + ws[WS_ZW1 + b*Ff + tid]    + b1[tid];
    base[tid+NT] = ws[WS_HW1 + b*Ff + tid+NT] + ws[WS_ZW1 + b*Ff + tid+NT] + b1[tid+NT];
    if (tid < Nn) rowt[tid] = (tid < t) ? (float)tg[b*Nn*Nn + t*Nn + tid] : 0.0f;
    psnext[tid] = 0.0f;
    __syncthreads();

    const int nr = (r < t) ? ((t - r + 7) >> 3) : 0;   // owned rows j = r+8i < t

    // ----- logits + log-likelihood (uses OLD S) -----
    for (int i0 = 0; i0 < nr; i0 += 8) {
      float a0[8], a1[8];
      #pragma unroll
      for (int ii = 0; ii < 8; ++ii) { a0[ii] = 0.0f; a1[ii] = 0.0f; }
      for (int k4 = 0; k4 < Hh/4; ++k4) {
        const unsigned wA0 = W1bp[(2*k4)*Ff + tid];
        const unsigned wB0 = W1bp[(2*k4)*Ff + tid + NT];
        const unsigned wA1 = W1bp[(2*k4+1)*Ff + tid];
        const unsigned wB1 = W1bp[(2*k4+1)*Ff + tid + NT];
        const float a0e=bf2f_lo(wA0), a0o=bf2f_hi(wA0), a1e=bf2f_lo(wA1), a1o=bf2f_hi(wA1);
        const float b0e=bf2f_lo(wB0), b0o=bf2f_hi(wB0), b1e=bf2f_lo(wB1), b1o=bf2f_hi(wB1);
        #pragma unroll
        for (int ii = 0; ii < 8; ++ii) {
          const float4 sv = *(const float4*)&S[i0+ii][4*k4];   // unowned rows are 0 -> harmless
          a0[ii] = fmaf(sv.x,a0e, fmaf(sv.y,a0o, fmaf(sv.z,a1e, fmaf(sv.w,a1o, a0[ii]))));
          a1[ii] = fmaf(sv.x,b0e, fmaf(sv.y,b0o, fmaf(sv.z,b1e, fmaf(sv.w,b1o, a1[ii]))));
        }
      }
      #pragma unroll
      for (int ii = 0; ii < 8; ++ii) {
        if (i0+ii < nr) {   // uniform across block
          const int j = r + 8*(i0+ii);
          float pp = fmaxf(a0[ii] + base[tid],    0.0f) * w2s[tid]
                   + fmaxf(a1[ii] + base[tid+NT], 0.0f) * w2s[tid+NT];
          float ap = (tid < Nn) ? rowt[tid] * (float)Ab[tid*Nn + j] : 0.0f;
          #pragma unroll
          for (int off = 32; off > 0; off >>= 1) {
            pp += __shfl_down(pp, off);
            ap += __shfl_down(ap, off);
          }
          if (lane == 0) { wred[wv][0] = pp; wred[wv][1] = ap; }
          __syncthreads();
          if (tid == 0) {
            const float logit = wred[0][0]+wred[1][0]+wred[2][0]+wred[3][0] + b2v;
            float anc = fminf(wred[0][1]+wred[1][1]+wred[2][1]+wred[3][1], 1.0f);
            float q = sigm(logit) * (1.0f - 0.5f*anc);
            q = fminf(fmaxf(q, 1e-6f), 1.0f - 1e-6f);
            const float rj = rowt[j];
            llacc += rj*logf(q) + (1.0f-rj)*log1pf(-q);
          }
          __syncthreads();
        }
      }
    }

    // ----- GRU propagate for owned rows j < t -----
    for (int i0 = 0; i0 < nr; i0 += 8) {
      float ar[8], au[8], an[8];
      #pragma unroll
      for (int ii = 0; ii < 8; ++ii) { ar[ii]=0.0f; au[ii]=0.0f; an[ii]=0.0f; }
      for (int k4 = 0; k4 < Hh/4; ++k4) {
        const unsigned wr0 = Whp[(2*k4)*Gg + tid];
        const unsigned wu0 = Whp[(2*k4)*Gg + 256 + tid];
        const unsigned wn0 = Whp[(2*k4)*Gg + 512 + tid];
        const unsigned wr1 = Whp[(2*k4+1)*Gg + tid];
        const unsigned wu1 = Whp[(2*k4+1)*Gg + 256 + tid];
        const unsigned wn1 = Whp[(2*k4+1)*Gg + 512 + tid];
        const float r0e=bf2f_lo(wr0), r0o=bf2f_hi(wr0), r1e=bf2f_lo(wr1), r1o=bf2f_hi(wr1);
        const float u0e=bf2f_lo(wu0), u0o=bf2f_hi(wu0), u1e=bf2f_lo(wu1), u1o=bf2f_hi(wu1);
        const float n0e=bf2f_lo(wn0), n0o=bf2f_hi(wn0), n1e=bf2f_lo(wn1), n1o=bf2f_hi(wn1);
        #pragma unroll
        for (int ii = 0; ii < 8; ++ii) {
          const float4 sv = *(const float4*)&S[i0+ii][4*k4];
          ar[ii] = fmaf(sv.x,r0e, fmaf(sv.y,r0o, fmaf(sv.z,r1e, fmaf(sv.w,r1o, ar[ii]))));
          au[ii] = fmaf(sv.x,u0e, fmaf(sv.y,u0o, fmaf(sv.z,u1e, fmaf(sv.w,u1o, au[ii]))));
          an[ii] = fmaf(sv.x,n0e, fmaf(sv.y,n0o, fmaf(sv.z,n1e, fmaf(sv.w,n1o, an[ii]))));
        }
      }
      __syncthreads();   // all reads of old S complete before overwrite
      float pacc = 0.0f;
      #pragma unroll
      for (int ii = 0; ii < 8; ++ii) {
        if (i0+ii < nr) {
          const int i = i0+ii;
          const float old = S[i][tid];
          const float rv = sigm(gx2s[tid]     + ar[ii] + bhr);
          const float uv = sigm(gx2s[256+tid] + au[ii] + bhu);
          const float nv = tanhf(gx2s[512+tid] + rv*(an[ii] + bhn));
          const float nsv = (1.0f-uv)*nv + uv*old;
          S[i][tid] = nsv;
          pacc += nsv;
        }
      }
      psnext[tid] += pacc;
      __syncthreads();
    }

    // ----- row t: set + propagate (h = h_prov), and ancestor row A[t] -----
    if ((t & 7) == r) {
      const int i = t >> 3;
      const float g0 = ws[WS_GHT + b*Gg + tid];
      const float g1 = ws[WS_GHT + b*Gg + 256 + tid];
      const float g2 = ws[WS_GHT + b*Gg + 512 + tid];
      const float rv = sigm(gx2s[tid] + g0);
      const float uv = sigm(gx2s[256+tid] + g1);
      const float nv = tanhf(gx2s[512+tid] + rv*g2);
      const float nsv = (1.0f-uv)*nv + uv*hpf[tid];
      S[i][tid] = nsv;
      psnext[tid] += nsv;
      if (tid < t) {
        float ra = 0.0f;
        for (int k = 0; k < t; ++k) ra += rowt[k] * (float)Ab[k*Nn + tid];
        Ab[t*Nn + tid] = (rowt[tid] + ra >= 0.5f) ? (unsigned char)1 : (unsigned char)0;
      }
    }
    __syncthreads();
    // pooled partial sum for step t+1 (plain store to this block's private slot)
    ws[WS_SLOTS + ((((t+1)&1)*Bz + b)*NBLK + r)*Hh + tid] = psnext[tid];
    bbarrier(bar, bseq);   // B3: end of step
  }

  if (tid == 0) atomicAdd(&out[Bz*Nn*Nn + b], llacc);
}

extern "C" void kernel_launch(void* const* d_in, const int* in_sizes, int n_in,
                              void* d_out, int out_size, void* d_ws, size_t ws_size,
                              hipStream_t stream)
{
  const float* z  = (const float*)d_in[0];
  const int*   tg = (const int*)  d_in[1];
  const float* Wi = (const float*)d_in[2];
  const float* bi = (const float*)d_in[3];
  const float* Wx = (const float*)d_in[4];
  const float* Wh = (const float*)d_in[5];
  const float* bx = (const float*)d_in[6];
  const float* bh = (const float*)d_in[7];
  const float* W1 = (const float*)d_in[8];
  const float* b1 = (const float*)d_in[9];
  const float* W2 = (const float*)d_in[10];
  const float* b2 = (const float*)d_in[11];
  float* out = (float*)d_out;
  float* ws  = (float*)d_ws;

  hipLaunchKernelGGL(prep_init, dim3(512), dim3(NT), 0, stream, tg, Wx, Wh, W1, ws, out);
  hipLaunchKernelGGL(prep_batch, dim3(Bz), dim3(NT), 0, stream, z, Wi, bi, Wh, bh, W1, ws);

  void* args[] = { (void*)&tg, (void*)&bx, (void*)&bh, (void*)&b1,
                   (void*)&W2, (void*)&b2, (void*)&ws, (void*)&out };
  hipLaunchCooperativeKernel((void*)decoder_main, dim3(Bz*NBLK), dim3(NT),
                             args, 0, stream);
}

// Round 2
// 12040.768 us; speedup vs baseline: 1.2855x; 1.2855x over previous
//
#include <hip/hip_runtime.h>
#include <math.h>

// Problem constants
#define Bz   32
#define Nn   128
#define Hh   256
#define Dd   256
#define Ff   512
#define Gg   768      // 3*H
#define NT   512      // threads per block (8 waves)
#define NTILES 80     // 48 GRU n-tiles (768/16) + 32 logit n-tiles (512/16)

typedef short v8s __attribute__((ext_vector_type(8)));   // 8 bf16 (4 VGPRs)
typedef float f4  __attribute__((ext_vector_type(4)));   // MFMA C/D

// Workspace layout (float elements)
#define WS_S     0                           // [B][128][256] fp32 master states
#define WS_H0    (WS_S + Bz*Nn*Hh)           // [B][256]
#define WS_GH0   (WS_H0 + Bz*Hh)             // [B][768]  h0@Wh+bh
#define WS_ZW1   (WS_GH0 + Bz*Gg)            // [B][512]  z@W1c
#define WS_WXP   (WS_ZW1 + Bz*Ff)            // [128][768] bf16-pair packed Wx (k2-major)
#define WS_W1AP  (WS_WXP + (Hh/2)*Gg)        // [128][512] packed W1 rows 0..255
#define WS_WBIG  (WS_W1AP + (Hh/2)*Ff)       // [80][8][64][4] uint: B-fragment-packed [Wh | W1b]
#define WS_TOTAL (WS_WBIG + NTILES*8*64*4)   // ~5.7 MB

__device__ __forceinline__ float bf2f_lo(unsigned w) { return __uint_as_float(w << 16); }
__device__ __forceinline__ float bf2f_hi(unsigned w) { return __uint_as_float(w & 0xffff0000u); }
__device__ __forceinline__ unsigned short f2bf(float x) {
  unsigned u = __float_as_uint(x);
  u = u + 0x7fffu + ((u >> 16) & 1u);   // RNE
  return (unsigned short)(u >> 16);
}
__device__ __forceinline__ unsigned pack2(float e, float o) {
  return (unsigned)f2bf(e) | ((unsigned)f2bf(o) << 16);
}
__device__ __forceinline__ float sigm(float x) { return 1.0f / (1.0f + __expf(-x)); }
__device__ __forceinline__ float tanh_fast(float x) { return 2.0f / (1.0f + __expf(-2.0f*x)) - 1.0f; }
__device__ __forceinline__ v8s u4_to_v8s(uint4 q) { union { uint4 q; v8s v; } c; c.q = q; return c.v; }

// ---------- prep 1: output L, zero states, pack weights ----------
__global__ void __launch_bounds__(256) prep_init(
    const int* __restrict__ tg, const float* __restrict__ Wx,
    const float* __restrict__ Wh, const float* __restrict__ W1,
    float* __restrict__ ws, float* __restrict__ out)
{
  const int stride = gridDim.x * blockDim.x;
  const int t0 = blockIdx.x * blockDim.x + threadIdx.x;

  for (int i = t0; i < Bz*Nn*Nn; i += stride) {         // L = tril(targets, -1)
    int col = i & (Nn-1), row = (i >> 7) & (Nn-1);
    out[i] = (col < row) ? (float)tg[i] : 0.0f;
  }
  for (int i = t0; i < Bz*Nn*Hh; i += stride) ws[WS_S + i] = 0.0f;

  unsigned* Wxp  = (unsigned*)(ws + WS_WXP);
  for (int i = t0; i < (Hh/2)*Gg; i += stride) {
    int k2 = i / Gg, c = i - k2*Gg;
    Wxp[i] = pack2(Wx[(2*k2)*Gg + c], Wx[(2*k2+1)*Gg + c]);
  }
  unsigned* W1ap = (unsigned*)(ws + WS_W1AP);
  for (int i = t0; i < (Hh/2)*Ff; i += stride) {
    int k2 = i / Ff, f = i - k2*Ff;
    W1ap[i] = pack2(W1[(2*k2)*Ff + f], W1[(2*k2+1)*Ff + f]);
  }
  // B-fragment packing: value for (lane l, uint jw) = W[k][n], k = ks*32 + (l>>4)*8 + 2*jw (+1),
  // n = nt*16 + (l&15).  nt<48 -> Wh[256][768]; nt>=48 -> W1 rows 256..511 ([256][512]).
  unsigned* Wb = (unsigned*)(ws + WS_WBIG);
  for (int i = t0; i < NTILES*8*64*4; i += stride) {
    int jw = i & 3, l = (i >> 2) & 63, ks = (i >> 8) & 7, nt = i >> 11;
    int k = ks*32 + (l >> 4)*8 + 2*jw;
    int c16 = l & 15;
    float lo, hi;
    if (nt < 48) { int n = nt*16 + c16;      lo = Wh[k*Gg + n];        hi = Wh[(k+1)*Gg + n]; }
    else         { int n = (nt-48)*16 + c16; lo = W1[(Hh+k)*Ff + n];   hi = W1[(Hh+k+1)*Ff + n]; }
    Wb[i] = pack2(lo, hi);
  }
}

// ---------- prep 2: per-batch h0, gh0 = h0@Wh+bh, zW1 = z@W1c (fp32) ----------
__global__ void __launch_bounds__(256) prep_batch(
    const float* __restrict__ z, const float* __restrict__ Wi,
    const float* __restrict__ bi, const float* __restrict__ Wh,
    const float* __restrict__ bh, const float* __restrict__ W1,
    float* __restrict__ ws)
{
  const int b = blockIdx.x, tid = threadIdx.x;
  __shared__ float zs[Dd], h0s[Hh];
  zs[tid] = z[b*Dd + tid];
  __syncthreads();
  float acc = bi[tid];
  for (int d = 0; d < Dd; ++d) acc = fmaf(zs[d], Wi[d*Hh + tid], acc);
  const float h0 = tanhf(acc);
  h0s[tid] = h0;
  ws[WS_H0 + b*Hh + tid] = h0;
  ws[WS_S + b*Nn*Hh + tid] = h0;          // states[0] = h0 (after prep_init zeroed S)
  __syncthreads();
  for (int g = tid; g < Gg; g += 256) {
    float a = bh[g];
    for (int h = 0; h < Hh; ++h) a = fmaf(h0s[h], Wh[h*Gg + g], a);
    ws[WS_GH0 + b*Gg + g] = a;
  }
  for (int f = tid; f < Ff; f += 256) {
    float a = 0.0f;
    for (int d = 0; d < Dd; ++d) a = fmaf(zs[d], W1[(2*Hh + d)*Ff + f], a);
    ws[WS_ZW1 + b*Ff + f] = a;
  }
}

// ---------- main: 1 block per batch, 8 waves, MFMA GEMMs, no inter-block sync ----------
__global__ void __launch_bounds__(NT) decoder_main(
    const int* __restrict__ tg,
    const float* __restrict__ bx, const float* __restrict__ bh,
    const float* __restrict__ b1, const float* __restrict__ W2,
    const float* __restrict__ b2,
    float* __restrict__ ws, float* __restrict__ out)
{
  const int b = blockIdx.x, tid = threadIdx.x;
  const int lane = tid & 63, wv = tid >> 6;
  const int c16 = lane & 15, quad = lane >> 4;

  float* __restrict__ Sb = ws + WS_S + b*Nn*Hh;
  const float* __restrict__ gh0g = ws + WS_GH0 + b*Gg;
  const float* __restrict__ zW1g = ws + WS_ZW1 + b*Ff;
  const float* __restrict__ h0g  = ws + WS_H0 + b*Hh;
  const unsigned* __restrict__ Wxp  = (const unsigned*)(ws + WS_WXP);
  const unsigned* __restrict__ W1ap = (const unsigned*)(ws + WS_W1AP);
  const uint4*    __restrict__ Wb4  = (const uint4*)(ws + WS_WBIG);

  __shared__ __align__(16) float psum[Hh], psnext[Hh], hpf[Hh], p2s[Hh], h0s[Hh];
  __shared__ __align__(16) float gxs[Gg], gx2s[Gg], bxs[Gg], bhs[Gg], gh0s[Gg];
  __shared__ __align__(16) float basef[Ff], w2s[Ff], zb1s[Ff];
  __shared__ float rowt[Nn], logitsf[Nn];
  __shared__ unsigned amask[Nn][4];   // ancestor bitset rows (128 bits each)
  __shared__ unsigned ancw[4];
  __shared__ float llacc;

  for (int i = tid; i < Gg; i += NT) { bxs[i] = bx[i]; bhs[i] = bh[i]; gh0s[i] = gh0g[i]; }
  for (int i = tid; i < Ff; i += NT) { w2s[i] = W2[i]; zb1s[i] = zW1g[i] + b1[i]; }
  for (int i = tid; i < Hh; i += NT) { float h = h0g[i]; h0s[i] = h; psum[i] = h; psnext[i] = 0.0f; }
  for (int i = tid; i < Nn*4; i += NT) ((unsigned*)amask)[i] = 0u;
  if (tid == 0) llacc = 0.0f;
  const float b2v = b2[0];
  __syncthreads();

  for (int t = 1; t < Nn; ++t) {
    const float invt  = 1.0f / (float)t;
    const float invt1 = 1.0f / (float)(t+1);

    // ---- phase 1a: gx = (psum@Wx)*invt + bx  (768 outputs) ----
    for (int c = tid; c < Gg; c += NT) {
      float acc = 0.0f;
      #pragma unroll 4
      for (int k2 = 0; k2 < Hh/2; ++k2) {
        const unsigned w = Wxp[k2*Gg + c];
        const float2 s = *(const float2*)&psum[2*k2];
        acc = fmaf(bf2f_lo(w), s.x, fmaf(bf2f_hi(w), s.y, acc));
      }
      gxs[c] = acc*invt + bxs[c];
    }
    __syncthreads();

    // ---- phase 1b: h_prov, S[t] write, pooled2; rowt load; zero scratch ----
    if (tid < Hh) {
      const float rv = sigm(gxs[tid] + gh0s[tid]);
      const float uv = sigm(gxs[Hh+tid] + gh0s[Hh+tid]);
      const float nv = tanh_fast(gxs[2*Hh+tid] + rv*gh0s[2*Hh+tid]);
      const float hp = (1.0f-uv)*nv + uv*h0s[tid];
      hpf[tid] = hp;
      Sb[t*Hh + tid] = hp;
      p2s[tid] = (psum[tid] + hp) * invt1;
    } else if (tid < Hh + Nn) {
      const int j = tid - Hh;
      rowt[j] = (j < t) ? (float)tg[b*Nn*Nn + t*Nn + j] : 0.0f;
      logitsf[j] = 0.0f;
    } else if (tid < Hh + Nn + 4) {
      ancw[tid - Hh - Nn] = 0u;
    }
    __syncthreads();

    // ---- phase 1c: gx2 = p2s@Wx + bx; base = hpf@W1a + zW1 + b1; ancestor OR ----
    for (int c = tid; c < Gg + Ff; c += NT) {
      float acc = 0.0f;
      if (c < Gg) {
        #pragma unroll 4
        for (int k2 = 0; k2 < Hh/2; ++k2) {
          const unsigned w = Wxp[k2*Gg + c];
          const float2 s = *(const float2*)&p2s[2*k2];
          acc = fmaf(bf2f_lo(w), s.x, fmaf(bf2f_hi(w), s.y, acc));
        }
        gx2s[c] = acc + bxs[c];
      } else {
        const int f = c - Gg;
        #pragma unroll 4
        for (int k2 = 0; k2 < Hh/2; ++k2) {
          const unsigned w = W1ap[k2*Ff + f];
          const float2 s = *(const float2*)&hpf[2*k2];
          acc = fmaf(bf2f_lo(w), s.x, fmaf(bf2f_hi(w), s.y, acc));
        }
        basef[f] = acc + zb1s[f];
      }
    }
    if (tid < Nn && tid < t && rowt[tid] > 0.5f) {
      atomicOr(&ancw[0], amask[tid][0]); atomicOr(&ancw[1], amask[tid][1]);
      atomicOr(&ancw[2], amask[tid][2]); atomicOr(&ancw[3], amask[tid][3]);
    }
    __syncthreads();

    // ---- phase 2: MFMA GEMMs per 16-row M-tile ----
    const int Mtot = (t + 16) >> 4;           // ceil((t+1)/16); row t included for GRU
    const int ht0 = 2*wv, ht1 = 2*wv + 1;     // this wave's GRU h-tiles (h-cols [32w,32w+32))
    for (int mt = 0; mt < Mtot; ++mt) {
      const int m0 = mt << 4;

      // A-fragments: 8 k-steps, built from fp32 states (rows > t are zero)
      v8s af[8];
      {
        const float* Sr = Sb + (m0 + c16)*Hh + quad*8;
        #pragma unroll
        for (int ks = 0; ks < 8; ++ks) {
          const float4 fa = *(const float4*)(Sr + ks*32);
          const float4 fb = *(const float4*)(Sr + ks*32 + 4);
          union { unsigned u[4]; v8s v; } cv;
          cv.u[0] = pack2(fa.x, fa.y); cv.u[1] = pack2(fa.z, fa.w);
          cv.u[2] = pack2(fb.x, fb.y); cv.u[3] = pack2(fb.z, fb.w);
          af[ks] = cv.v;
        }
      }
      __syncthreads();   // all A-reads complete before any wave writes S below

      // GRU GEMM: 6 independent accumulator chains (r,u,n gates x 2 h-tiles)
      f4 cR0 = {0,0,0,0}, cR1 = {0,0,0,0}, cU0 = {0,0,0,0};
      f4 cU1 = {0,0,0,0}, cN0 = {0,0,0,0}, cN1 = {0,0,0,0};
      #pragma unroll
      for (int ks = 0; ks < 8; ++ks) {
        const v8s a = af[ks];
        const uint4 br0 = Wb4[((ht0     )*8 + ks)*64 + lane];
        const uint4 br1 = Wb4[((ht1     )*8 + ks)*64 + lane];
        const uint4 bu0 = Wb4[((16 + ht0)*8 + ks)*64 + lane];
        const uint4 bu1 = Wb4[((16 + ht1)*8 + ks)*64 + lane];
        const uint4 bn0 = Wb4[((32 + ht0)*8 + ks)*64 + lane];
        const uint4 bn1 = Wb4[((32 + ht1)*8 + ks)*64 + lane];
        cR0 = __builtin_amdgcn_mfma_f32_16x16x32_bf16(a, u4_to_v8s(br0), cR0, 0, 0, 0);
        cR1 = __builtin_amdgcn_mfma_f32_16x16x32_bf16(a, u4_to_v8s(br1), cR1, 0, 0, 0);
        cU0 = __builtin_amdgcn_mfma_f32_16x16x32_bf16(a, u4_to_v8s(bu0), cU0, 0, 0, 0);
        cU1 = __builtin_amdgcn_mfma_f32_16x16x32_bf16(a, u4_to_v8s(bu1), cU1, 0, 0, 0);
        cN0 = __builtin_amdgcn_mfma_f32_16x16x32_bf16(a, u4_to_v8s(bn0), cN0, 0, 0, 0);
        cN1 = __builtin_amdgcn_mfma_f32_16x16x32_bf16(a, u4_to_v8s(bn1), cN1, 0, 0, 0);
      }

      // Logits GEMM: 4 chains (f-cols [64w, 64w+64))
      const bool doLog = (m0 < t);
      f4 cL0 = {0,0,0,0}, cL1 = {0,0,0,0}, cL2 = {0,0,0,0}, cL3 = {0,0,0,0};
      if (doLog) {
        const int ntL = 48 + 4*wv;
        #pragma unroll
        for (int ks = 0; ks < 8; ++ks) {
          const v8s a = af[ks];
          const uint4 b0 = Wb4[((ntL  )*8 + ks)*64 + lane];
          const uint4 b1v = Wb4[((ntL+1)*8 + ks)*64 + lane];
          const uint4 b2q = Wb4[((ntL+2)*8 + ks)*64 + lane];
          const uint4 b3 = Wb4[((ntL+3)*8 + ks)*64 + lane];
          cL0 = __builtin_amdgcn_mfma_f32_16x16x32_bf16(a, u4_to_v8s(b0),  cL0, 0, 0, 0);
          cL1 = __builtin_amdgcn_mfma_f32_16x16x32_bf16(a, u4_to_v8s(b1v), cL1, 0, 0, 0);
          cL2 = __builtin_amdgcn_mfma_f32_16x16x32_bf16(a, u4_to_v8s(b2q), cL2, 0, 0, 0);
          cL3 = __builtin_amdgcn_mfma_f32_16x16x32_bf16(a, u4_to_v8s(b3),  cL3, 0, 0, 0);
        }
      }

      // GRU pointwise epilogue (registers only; wave owns its h-cols exclusively)
      #pragma unroll
      for (int half = 0; half < 2; ++half) {
        const int h = (half ? ht1 : ht0)*16 + c16;
        const f4 cr = half ? cR1 : cR0;
        const f4 cu = half ? cU1 : cU0;
        const f4 cn = half ? cN1 : cN0;
        const float gxr = gx2s[h], gxu = gx2s[Hh+h], gxn = gx2s[2*Hh+h];
        const float bhr = bhs[h], bhu = bhs[Hh+h], bhn = bhs[2*Hh+h];
        float colsum = 0.0f;
        #pragma unroll
        for (int rg = 0; rg < 4; ++rg) {
          const int row = m0 + quad*4 + rg;
          if (row <= t) {
            const float old = Sb[row*Hh + h];
            const float rv = sigm(gxr + cr[rg] + bhr);
            const float uv = sigm(gxu + cu[rg] + bhu);
            const float nv = tanh_fast(gxn + rv*(cn[rg] + bhn));
            const float ns = (1.0f-uv)*nv + uv*old;
            Sb[row*Hh + h] = ns;
            colsum += ns;
          }
        }
        colsum += __shfl_down(colsum, 16);
        colsum += __shfl_down(colsum, 32);
        if (quad == 0) atomicAdd(&psnext[h], colsum);
      }

      // Logits epilogue: relu(C+base)*w2, reduce over f, accumulate per row
      if (doLog) {
        float racc[4] = {0,0,0,0};
        #pragma unroll
        for (int ft = 0; ft < 4; ++ft) {
          const int f = (4*wv + ft)*16 + c16;
          const f4 cl = (ft==0) ? cL0 : (ft==1) ? cL1 : (ft==2) ? cL2 : cL3;
          const float bs = basef[f], w2 = w2s[f];
          #pragma unroll
          for (int rg = 0; rg < 4; ++rg)
            racc[rg] += fmaxf(cl[rg] + bs, 0.0f) * w2;
        }
        #pragma unroll
        for (int rg = 0; rg < 4; ++rg) {
          float v = racc[rg];
          v += __shfl_xor(v, 1); v += __shfl_xor(v, 2);
          v += __shfl_xor(v, 4); v += __shfl_xor(v, 8);
          const int row = m0 + quad*4 + rg;
          if (c16 == 0 && row < t) atomicAdd(&logitsf[row], v);
        }
      }
    }
    __syncthreads();

    // ---- phase 3: log-likelihood, ancestor row t, pooled swap ----
    float term = 0.0f;
    if (tid < t) {
      const float anc = (float)((ancw[tid >> 5] >> (tid & 31)) & 1u);
      float q = sigm(logitsf[tid] + b2v) * (1.0f - 0.5f*anc);
      q = fminf(fmaxf(q, 1e-6f), 1.0f - 1e-6f);
      term = rowt[tid]*logf(q) + (1.0f - rowt[tid])*log1pf(-q);
    }
    if (wv < 2) {
      #pragma unroll
      for (int off = 32; off; off >>= 1) term += __shfl_down(term, off);
      if (lane == 0) atomicAdd(&llacc, term);
      const unsigned long long bal = __ballot(tid < t && rowt[tid] > 0.5f);
      if (lane == 0) {
        amask[t][2*wv]   = (unsigned)bal         | ancw[2*wv];
        amask[t][2*wv+1] = (unsigned)(bal >> 32) | ancw[2*wv+1];
      }
    }
    __syncthreads();
    if (tid < Hh) { psum[tid] = psnext[tid]; psnext[tid] = 0.0f; }
    __syncthreads();
  }

  if (tid == 0) out[Bz*Nn*Nn + b] = llacc;
}

extern "C" void kernel_launch(void* const* d_in, const int* in_sizes, int n_in,
                              void* d_out, int out_size, void* d_ws, size_t ws_size,
                              hipStream_t stream)
{
  const float* z  = (const float*)d_in[0];
  const int*   tg = (const int*)  d_in[1];
  const float* Wi = (const float*)d_in[2];
  const float* bi = (const float*)d_in[3];
  const float* Wx = (const float*)d_in[4];
  const float* Wh = (const float*)d_in[5];
  const float* bx = (const float*)d_in[6];
  const float* bh = (const float*)d_in[7];
  const float* W1 = (const float*)d_in[8];
  const float* b1 = (const float*)d_in[9];
  const float* W2 = (const float*)d_in[10];
  const float* b2 = (const float*)d_in[11];
  float* out = (float*)d_out;
  float* ws  = (float*)d_ws;

  hipLaunchKernelGGL(prep_init, dim3(512), dim3(256), 0, stream, tg, Wx, Wh, W1, ws, out);
  hipLaunchKernelGGL(prep_batch, dim3(Bz), dim3(256), 0, stream, z, Wi, bi, Wh, bh, W1, ws);
  hipLaunchKernelGGL(decoder_main, dim3(Bz), dim3(NT), 0, stream,
                     tg, bx, bh, b1, W2, b2, ws, out);
}